// Round 8
// baseline (1072.159 us; speedup 1.0000x reference)
//
#include <hip/hip_runtime.h>

#define LSEQ 400
#define BATCH 256
#define EMBD 256
#define HIDD 512
#define KDIM 768   // EMB + HID
#define NJ 41      // K+1
#define RLX __ATOMIC_RELAXED
#define AGT __HIP_MEMORY_SCOPE_AGENT

typedef __attribute__((ext_vector_type(8))) short short8x;
typedef __attribute__((ext_vector_type(4))) float f32x4;
typedef unsigned long long u64;

union BQ { short8x v; unsigned short u[8]; u64 q[2]; };

__device__ __forceinline__ float bf2f(unsigned short u) {
    union { unsigned int i; float f; } v; v.i = ((unsigned int)u) << 16; return v.f;
}
__device__ __forceinline__ unsigned short f2bf(float f) {
    union { float f; unsigned int i; } v; v.f = f;
    unsigned int x = v.i;
    return (unsigned short)((x + 0x7fffu + ((x >> 16) & 1u)) >> 16);
}
__device__ __forceinline__ float sigm(float x) { return 1.0f / (1.0f + __expf(-x)); }

__device__ __forceinline__ u64 ald(const u64* p) {
    return __hip_atomic_load((u64*)p, RLX, AGT);
}
__device__ __forceinline__ void ast(u64* p, u64 v) {
    __hip_atomic_store(p, v, RLX, AGT);
}

// ---------------------------------------------------------------------------
// Prologue: pack W into bf16 fragments [rg(32)][w(4)][kt(24)][lane(64)];
// zero h-region of xh buffer 0; zero flags/base_rows. (x-region of xh is now
// unused — x lives only in LDS, gathered locally per WG.)
// ---------------------------------------------------------------------------
__global__ __launch_bounds__(256) void prologue_kernel(
    const float* __restrict__ W_ih, const float* __restrict__ W_hh,
    unsigned short* __restrict__ pW, unsigned short* __restrict__ xh0,
    int* __restrict__ base_rows, unsigned* __restrict__ flags)
{
    int wid = blockIdx.x, t = threadIdx.x;
    int rg = wid >> 3, sub = wid & 7;
    int lane = t & 63, subw = t >> 6;
    for (int q = 0; q < 3; ++q) {
        int G = sub * 12 + subw * 3 + q;     // 0..95 = w(4) x kt(24)
        int w = G / 24, kt = G % 24;
        int grow = w * 512 + rg * 16 + (lane & 15);
        int k0 = kt * 32 + ((lane >> 4) << 3);
        BQ pk;
        #pragma unroll
        for (int j = 0; j < 8; ++j) {
            int k = k0 + j;
            float wv = (k < EMBD) ? W_ih[(size_t)grow * EMBD + k]
                                  : W_hh[(size_t)grow * HIDD + (k - EMBD)];
            pk.u[j] = f2bf(wv);
        }
        ((short8x*)pW)[((size_t)(rg * 4 + w) * 24 + kt) * 64 + lane] = pk.v;
    }
    int b = wid;
    for (int e = t; e < HIDD; e += 256) xh0[(size_t)b * KDIM + EMBD + e] = 0;
    if (t == 0) base_rows[b] = 0;
    if (t < 32) flags[wid * 32 + t] = 0u;
}

// ---------------------------------------------------------------------------
// Persistent kernel. 256 WGs = 8 col-groups (cg) x 32 row-groups (rg).
// WG(cg,rg): 64 gate rows x 32 cols; owns col colg=cg*32+rg for boundary/loss.
// x-part of B gathered LOCALLY per WG from embW/mask (rows deterministic from
// brs); only h (512k) goes through the sc1 exchange + 32-WG flag barrier.
// ---------------------------------------------------------------------------
__global__ __launch_bounds__(256, 1) void persistent_kernel(
    const unsigned short* __restrict__ pW,
    unsigned short* __restrict__ xh,           // 2 double-buffered [256][768] (h-region only used)
    int* __restrict__ base_rows,
    const float* __restrict__ b_ih, const float* __restrict__ b_hh,
    const int* __restrict__ xs, const float* __restrict__ embW,
    const float* __restrict__ mask,
    const float* __restrict__ W_jump, const float* __restrict__ b_jump,
    const float* __restrict__ W_base, const float* __restrict__ b_base,
    const float* __restrict__ gumbel,
    float* __restrict__ lp_arr, float* __restrict__ base_arr,
    const float* __restrict__ W_out, const float* __restrict__ b_out,
    const int* __restrict__ tcls,
    float* __restrict__ loss_arr, unsigned* __restrict__ flags)
{
    __shared__ u64 Bsh[32 * 193];                 // [32 cols][772 shorts]; x=qw 0..63, h=qw 64..191
    __shared__ float gates[4][16][33];            // [gate][unit][col+pad]
    __shared__ __align__(8) unsigned short hstage[32][16];   // [col][unit]
    __shared__ int brs[32];                       // base rows of this cg's cols
    __shared__ float zsh[42];
    __shared__ int nbrsh;

    const int wg = blockIdx.x;
    const int cg = wg >> 5, rg = wg & 31;
    const int colbase = cg * 32;
    const int colg = colbase + rg;                // owned column
    const int tid = threadIdx.x, lane = tid & 63, w = tid >> 6;

    // --- A fragments resident (24 x short8x per wave) ---
    short8x A[24];
    {
        const short8x* Ab = ((const short8x*)pW) + ((size_t)(rg * 4 + w) * 24) * 64 + lane;
        #pragma unroll
        for (int kt = 0; kt < 24; ++kt) A[kt] = Ab[kt * 64];
    }

    // --- elementwise mapping: unit u = tid>>4, two local cols lc0, lc0+1 ---
    const int u = tid >> 4;
    const int lc0 = (tid & 15) << 1;
    const int hid = rg * 16 + u;
    const float bi  = b_ih[hid]        + b_hh[hid];
    const float bf_ = b_ih[512 + hid]  + b_hh[512 + hid];
    const float bgt = b_ih[1024 + hid] + b_hh[1024 + hid];
    const float bo  = b_ih[1536 + hid] + b_hh[1536 + hid];

    // --- gather mapping: col gc = tid>>3, 32-elem segment seg = tid&7 ---
    const int gc = tid >> 3, seg = tid & 7;
    u64* const gdst = &Bsh[(size_t)gc * 193 + seg * 8];

    // --- staging mapping (h-part): col = j*2 + (tid>>7), qw off = tid&127 ---
    const int sc2 = tid >> 7, sqo = tid & 127;
    u64* const sdst0 = &Bsh[(size_t)sc2 * 193 + 64 + sqo];

    float c0 = 0.f, c1 = 0.f, h0 = 0.f, h1 = 0.f;
    int brc0 = 0, brc1 = 0;

    unsigned bar = 0;
    const size_t XH = (size_t)BATCH * KDIM;
    int p = 0;

    if (tid < 32) brs[tid] = 0;
    __syncthreads();

    // initial x (i=0, rows 0): full local gather
    {
        int row = brs[gc]; if (row > LSEQ - 1) row = LSEQ - 1;
        int tok = xs[(size_t)row * BATCH + colbase + gc];
        const float4* ep = (const float4*)(embW + (size_t)tok * EMBD + seg * 32);
        const float4* mp = (const float4*)(mask + ((size_t)row * BATCH + colbase + gc) * EMBD + seg * 32);
        #pragma unroll
        for (int q = 0; q < 8; ++q) {
            float4 e = ep[q], m = mp[q];
            u64 pk = (u64)f2bf(e.x * m.x) | ((u64)f2bf(e.y * m.y) << 16)
                   | ((u64)f2bf(e.z * m.z) << 32) | ((u64)f2bf(e.w * m.w) << 48);
            gdst[q] = pk;
        }
    }

    for (int n = 0; n < 5; ++n) {
        for (int i = 0; i <= 20; ++i) {
            const unsigned short* xin  = xh + (size_t)p * XH;
            unsigned short*       xout = xh + (size_t)(p ^ 1) * XH;

            // (1) issue next-x gather loads early (consumed after MFMA sync)
            float4 ge[8], gm[8];
            if (i < 20) {
                int row = brs[gc] + i + 1; if (row > LSEQ - 1) row = LSEQ - 1;
                int tok = xs[(size_t)row * BATCH + colbase + gc];
                const float4* ep = (const float4*)(embW + (size_t)tok * EMBD + seg * 32);
                const float4* mp = (const float4*)(mask + ((size_t)row * BATCH + colbase + gc) * EMBD + seg * 32);
                #pragma unroll
                for (int q = 0; q < 8; ++q) { ge[q] = ep[q]; gm[q] = mp[q]; }
            }

            // (2) stage h-part (32 cols x 512k = 4096 u64) sc1 -> LDS
            {
                const u64* xin64 = (const u64*)xin;
                #pragma unroll
                for (int j = 0; j < 16; ++j) {
                    int col = j * 2 + sc2;
                    sdst0[(size_t)(j * 2) * 193] =
                        ald(xin64 + (size_t)(colbase + col) * 96 + 32 + sqo);
                }
            }
            __syncthreads();

            // (3) MFMA: wave w = gate w; 2 n-tiles; dual kt chains
            f32x4 aA0 = {0,0,0,0}, aB0 = {0,0,0,0};
            f32x4 aA1 = {0,0,0,0}, aB1 = {0,0,0,0};
            {
                const u64* bc0 = &Bsh[(size_t)(lane & 15) * 193 + ((lane >> 4) << 1)];
                const u64* bc1 = bc0 + 16 * 193;
                #pragma unroll
                for (int kt = 0; kt < 24; kt += 2) {
                    BQ q00, q10, q01, q11;
                    q00.q[0] = bc0[kt * 8];     q00.q[1] = bc0[kt * 8 + 1];
                    q10.q[0] = bc1[kt * 8];     q10.q[1] = bc1[kt * 8 + 1];
                    q01.q[0] = bc0[kt * 8 + 8]; q01.q[1] = bc0[kt * 8 + 9];
                    q11.q[0] = bc1[kt * 8 + 8]; q11.q[1] = bc1[kt * 8 + 9];
                    aA0 = __builtin_amdgcn_mfma_f32_16x16x32_bf16(A[kt],     q00.v, aA0, 0, 0, 0);
                    aA1 = __builtin_amdgcn_mfma_f32_16x16x32_bf16(A[kt],     q10.v, aA1, 0, 0, 0);
                    aB0 = __builtin_amdgcn_mfma_f32_16x16x32_bf16(A[kt + 1], q01.v, aB0, 0, 0, 0);
                    aB1 = __builtin_amdgcn_mfma_f32_16x16x32_bf16(A[kt + 1], q11.v, aB1, 0, 0, 0);
                }
            }
            f32x4 acc0 = aA0 + aB0, acc1 = aA1 + aB1;
            {
                int ur = (lane >> 4) << 2;
                int cl = lane & 15;
                #pragma unroll
                for (int v = 0; v < 4; ++v) {   // D: unit=(lane>>4)*4+v, col=lane&15
                    gates[w][ur + v][cl]      = acc0[v];
                    gates[w][ur + v][cl + 16] = acc1[v];
                }
            }
            __syncthreads();

            // (4) write next-x into Bsh x-region (this step's MFMA done reading)
            if (i < 20) {
                #pragma unroll
                for (int q = 0; q < 8; ++q) {
                    u64 pk = (u64)f2bf(ge[q].x * gm[q].x) | ((u64)f2bf(ge[q].y * gm[q].y) << 16)
                           | ((u64)f2bf(ge[q].z * gm[q].z) << 32) | ((u64)f2bf(ge[q].w * gm[q].w) << 48);
                    gdst[q] = pk;
                }
            }

            // (5) elementwise LSTM on resident state (2 cols)
            {
                bool fp = (brc0 + i) >= LSEQ;
                float gi = gates[0][u][lc0] + bi;
                float gf = gates[1][u][lc0] + bf_;
                float gc_ = gates[2][u][lc0] + bgt;
                float go = gates[3][u][lc0] + bo;
                float c2 = sigm(gf) * c0 + sigm(gi) * tanhf(gc_);
                float h2 = sigm(go) * tanhf(c2);
                if (!fp) { c0 = c2; h0 = h2; }
                hstage[lc0][u] = f2bf(h0);
            }
            {
                bool fp = (brc1 + i) >= LSEQ;
                float gi = gates[0][u][lc0 + 1] + bi;
                float gf = gates[1][u][lc0 + 1] + bf_;
                float gc_ = gates[2][u][lc0 + 1] + bgt;
                float go = gates[3][u][lc0 + 1] + bo;
                float c2 = sigm(gf) * c1 + sigm(gi) * tanhf(gc_);
                float h2 = sigm(go) * tanhf(c2);
                if (!fp) { c1 = c2; h1 = h2; }
                hstage[lc0 + 1][u] = f2bf(h1);
            }
            __syncthreads();

            // (6) sc1 stores: h slice (16 units x 32 cols)
            if (tid < 128) {
                int col = tid >> 2, qd = tid & 3;
                u64 hv = ((const u64*)&hstage[col][0])[qd];
                ast((u64*)(xout + (size_t)(colbase + col) * KDIM + EMBD + rg * 16) + qd, hv);
            }
            p ^= 1;

            // (7) per-col-group barrier (32 padded flags)
            ++bar;
            asm volatile("s_waitcnt vmcnt(0) lgkmcnt(0)" ::: "memory");
            __syncthreads();
            if (tid == 0) __hip_atomic_store(&flags[wg * 32], bar, RLX, AGT);
            if (tid < 32) {
                while (__hip_atomic_load(&flags[(colbase + tid) * 32], RLX, AGT) < bar)
                    __builtin_amdgcn_s_sleep(1);
            }
            __syncthreads();

            if (i == 20) {
                // ---------------- boundary (owned col) ----------------------
                unsigned short* xcur = xh + (size_t)p * XH;
                BQ hv;
                const u64* hq = (const u64*)(xcur + (size_t)colg * KDIM + EMBD) + lane * 2;
                hv.q[0] = ald(hq);
                hv.q[1] = ald(hq + 1);
                float hf[8];
                #pragma unroll
                for (int q = 0; q < 8; ++q) hf[q] = bf2f(hv.u[q]);

                for (int r = w; r < 42; r += 4) {
                    const float* wr = (r < NJ) ? (W_jump + (size_t)r * HIDD) : W_base;
                    const float4* wp = (const float4*)(wr + lane * 8);
                    float4 w0 = wp[0], w1 = wp[1];
                    float acc = w0.x*hf[0] + w0.y*hf[1] + w0.z*hf[2] + w0.w*hf[3]
                              + w1.x*hf[4] + w1.y*hf[5] + w1.z*hf[6] + w1.w*hf[7];
                    #pragma unroll
                    for (int off = 32; off > 0; off >>= 1) acc += __shfl_down(acc, off, 64);
                    if (lane == 0) zsh[r] = acc + ((r < NJ) ? b_jump[r] : b_base[0]);
                }
                __syncthreads();

                if (tid == 0) {
                    const float* g = gumbel + ((size_t)n * BATCH + colg) * NJ;
                    float m = -1e30f, mg = -1e30f; int jm = 0;
                    for (int r = 0; r < NJ; ++r) {
                        float z = zsh[r];
                        if (z > m) m = z;
                        float zg = z + g[r];
                        if (zg > mg) { mg = zg; jm = r; }   // strict > tiebreak
                    }
                    float s = 0.0f;
                    for (int r = 0; r < NJ; ++r) s += expf(zsh[r] - m);
                    float lse = m + logf(s);
                    int br = brs[rg];                      // own base row
                    bool fp = (br + 20) >= LSEQ;
                    lp_arr[n * BATCH + colg]   = fp ? 0.0f : (zsh[jm] - lse);
                    base_arr[n * BATCH + colg] = zsh[41];
                    int reff = br + 20; if (reff > LSEQ - 1) reff = LSEQ - 1;
                    int nbr = (jm == 0) ? LSEQ : (reff + jm);
                    __hip_atomic_store(&base_rows[colg], nbr, RLX, AGT);
                }
                __syncthreads();

                // barrier #2: publish base_rows, then refresh brs + gather x(0)
                ++bar;
                asm volatile("s_waitcnt vmcnt(0) lgkmcnt(0)" ::: "memory");
                __syncthreads();
                if (tid == 0) __hip_atomic_store(&flags[wg * 32], bar, RLX, AGT);
                if (tid < 32) {
                    while (__hip_atomic_load(&flags[(colbase + tid) * 32], RLX, AGT) < bar)
                        __builtin_amdgcn_s_sleep(1);
                }
                __syncthreads();
                if (tid < 32) {
                    int v = __hip_atomic_load(&base_rows[colbase + tid], RLX, AGT);
                    brs[tid] = v;
                }
                __syncthreads();
                brc0 = brs[lc0];
                brc1 = brs[lc0 + 1];
                if (n < 4) {
                    int row = brs[gc]; if (row > LSEQ - 1) row = LSEQ - 1;
                    int tok = xs[(size_t)row * BATCH + colbase + gc];
                    const float4* ep = (const float4*)(embW + (size_t)tok * EMBD + seg * 32);
                    const float4* mp = (const float4*)(mask + ((size_t)row * BATCH + colbase + gc) * EMBD + seg * 32);
                    #pragma unroll
                    for (int q = 0; q < 8; ++q) {
                        float4 e = ep[q], m = mp[q];
                        u64 pk = (u64)f2bf(e.x * m.x) | ((u64)f2bf(e.y * m.y) << 16)
                               | ((u64)f2bf(e.z * m.z) << 32) | ((u64)f2bf(e.w * m.w) << 48);
                        gdst[q] = pk;
                    }
                }
            }
        }
    }

    // ---------------- final: per-col loss (owned col) -----------------------
    {
        const unsigned short* xcur = xh + (size_t)p * XH;
        BQ hv;
        const u64* hq = (const u64*)(xcur + (size_t)colg * KDIM + EMBD) + lane * 2;
        hv.q[0] = ald(hq);
        hv.q[1] = ald(hq + 1);
        float hf[8];
        #pragma unroll
        for (int q = 0; q < 8; ++q) hf[q] = bf2f(hv.u[q]);

        for (int r = w; r < 5; r += 4) {
            const float4* wp = (const float4*)(W_out + (size_t)r * HIDD + lane * 8);
            float4 w0 = wp[0], w1 = wp[1];
            float acc = w0.x*hf[0] + w0.y*hf[1] + w0.z*hf[2] + w0.w*hf[3]
                      + w1.x*hf[4] + w1.y*hf[5] + w1.z*hf[6] + w1.w*hf[7];
            #pragma unroll
            for (int off = 32; off > 0; off >>= 1) acc += __shfl_down(acc, off, 64);
            if (lane == 0) zsh[r] = acc + b_out[r];
        }
        __syncthreads();

        if (tid == 0) {
            float y[5];
            #pragma unroll
            for (int c = 0; c < 5; ++c) y[c] = zsh[c];
            float m = y[0]; int am = 0;
            for (int c = 1; c < 5; ++c) if (y[c] > m) { m = y[c]; am = c; }
            float s = 0.0f;
            for (int c = 0; c < 5; ++c) s += expf(y[c] - m);
            float lse = m + logf(s);
            int tb = tcls[colg];
            float nll_p  = -(y[tb] - lse) * (1.0f / BATCH);
            float reward = (am == tb) ? 1.0f : -1.0f;
            float rp = 0.0f, mp = 0.0f;
            for (int nn = 0; nn < 5; ++nn) {
                float bs = base_arr[nn * BATCH + colg];
                float lp = lp_arr[nn * BATCH + colg];
                rp += -(reward - bs) * lp;
                float d = bs - reward;
                mp += d * d;
            }
            loss_arr[colg] = nll_p + rp * (1.0f / (5.0f * BATCH)) + mp;
        }
    }
}

// ---------------------------------------------------------------------------
__global__ __launch_bounds__(256) void reduce_kernel(
    const float* __restrict__ loss_arr, float* __restrict__ out)
{
    __shared__ float red[256];
    int t = threadIdx.x;
    red[t] = loss_arr[t];
    __syncthreads();
    for (int off = 128; off > 0; off >>= 1) {
        if (t < off) red[t] += red[t + off];
        __syncthreads();
    }
    if (t == 0) out[0] = red[0];
}

// ---------------------------------------------------------------------------
extern "C" void kernel_launch(void* const* d_in, const int* in_sizes, int n_in,
                              void* d_out, int out_size, void* d_ws, size_t ws_size,
                              hipStream_t stream)
{
    (void)in_sizes; (void)n_in; (void)out_size; (void)ws_size;
    const int*   xs     = (const int*)d_in[0];
    const int*   tcls   = (const int*)d_in[2];
    const float* embW   = (const float*)d_in[3];
    const float* W_ih   = (const float*)d_in[4];
    const float* W_hh   = (const float*)d_in[5];
    const float* b_ih   = (const float*)d_in[6];
    const float* b_hh   = (const float*)d_in[7];
    const float* W_out  = (const float*)d_in[8];
    const float* b_out  = (const float*)d_in[9];
    const float* W_jump = (const float*)d_in[10];
    const float* b_jump = (const float*)d_in[11];
    const float* W_base = (const float*)d_in[12];
    const float* b_base = (const float*)d_in[13];
    const float* mask   = (const float*)d_in[14];
    const float* gumbel = (const float*)d_in[15];

    char* wsp = (char*)d_ws;
    unsigned short* pW  = (unsigned short*)(wsp);                 // 3,145,728 B
    unsigned short* xh  = (unsigned short*)(wsp + 3145728);       //   786,432 B
    int*      base_rows = (int*)(wsp + 3932160);                  //     1,024 B
    float*    lp_arr    = (float*)(wsp + 3933184);                //     5,120 B
    float*    base_arr  = (float*)(wsp + 3938304);                //     5,120 B
    float*    loss_arr  = (float*)(wsp + 3943424);                //     1,024 B
    unsigned* flags     = (unsigned*)(wsp + 3944448);             //    32,768 B
    float*    outp      = (float*)d_out;

    prologue_kernel<<<256, 256, 0, stream>>>(W_ih, W_hh, pW, xh, base_rows, flags);

    void* args[] = {
        (void*)&pW, (void*)&xh, (void*)&base_rows,
        (void*)&b_ih, (void*)&b_hh, (void*)&xs, (void*)&embW, (void*)&mask,
        (void*)&W_jump, (void*)&b_jump, (void*)&W_base, (void*)&b_base,
        (void*)&gumbel, (void*)&lp_arr, (void*)&base_arr,
        (void*)&W_out, (void*)&b_out, (void*)&tcls,
        (void*)&loss_arr, (void*)&flags
    };
    hipError_t err = hipLaunchCooperativeKernel((const void*)persistent_kernel,
                                                dim3(256), dim3(256), args, 0, stream);
    if (err != hipSuccess) {
        persistent_kernel<<<256, 256, 0, stream>>>(
            pW, xh, base_rows, b_ih, b_hh, xs, embW, mask,
            W_jump, b_jump, W_base, b_base, gumbel, lp_arr, base_arr,
            W_out, b_out, tcls, loss_arr, flags);
    }
    reduce_kernel<<<1, 256, 0, stream>>>(loss_arr, outp);
}

// Round 10
// 497.337 us; speedup vs baseline: 2.1558x; 2.1558x over previous
//
#include <hip/hip_runtime.h>

#define LSEQ 400
#define BATCH 256
#define EMBD 256
#define HIDD 512
#define KDIM 768   // EMB + HID
#define NJ 41      // K+1
#define RLX __ATOMIC_RELAXED
#define AGT __HIP_MEMORY_SCOPE_AGENT

typedef __attribute__((ext_vector_type(8))) short short8x;
typedef __attribute__((ext_vector_type(4))) float f32x4;
typedef __attribute__((ext_vector_type(4))) unsigned int u32x4;
typedef unsigned long long u64;

union BQ { short8x v; unsigned short u[8]; u64 q[2]; };
union BX { u32x4 v; unsigned short u[8]; u64 q[2]; };

__device__ __forceinline__ float bf2f(unsigned short u) {
    union { unsigned int i; float f; } v; v.i = ((unsigned int)u) << 16; return v.f;
}
__device__ __forceinline__ unsigned short f2bf(float f) {
    union { float f; unsigned int i; } v; v.f = f;
    unsigned int x = v.i;
    return (unsigned short)((x + 0x7fffu + ((x >> 16) & 1u)) >> 16);
}
__device__ __forceinline__ float sigm(float x) { return 1.0f / (1.0f + __expf(-x)); }

__device__ __forceinline__ void ast(u64* p, u64 v) {        // agent store (8B, compiler bits)
    __hip_atomic_store(p, v, RLX, AGT);
}
// agent-coherent 16B load (sc1 = L1/L2 bypass to coherent point; same
// visibility class the compiler emits for relaxed agent atomic loads)
#define ALD16(dst, addr) \
    asm volatile("global_load_dwordx4 %0, %1, off sc1" : "=&v"(dst) : "v"(addr) : "memory")

// ---------------------------------------------------------------------------
// Prologue: pack W into bf16 fragments [rg(16)][w(4)][m(2)][kt(24)][lane(64)].
// Wave w = gate w; m-tile m covers units rg*32 + m*16 + (lane&15);
// k = kt*32 + (lane>>4)*8 + j (proven bijection). Init x(row0)/h/flags.
// ---------------------------------------------------------------------------
__global__ __launch_bounds__(256) void prologue_kernel(
    const float* __restrict__ W_ih, const float* __restrict__ W_hh,
    const int* __restrict__ xs, const float* __restrict__ embW,
    const float* __restrict__ mask,
    unsigned short* __restrict__ pW, unsigned short* __restrict__ xh0,
    int* __restrict__ base_rows, unsigned* __restrict__ flags)
{
    int wid = blockIdx.x, t = threadIdx.x;
    int lane = t & 63, subw = t >> 6;
    int gw = wid * 4 + subw;                 // 0..1023
    for (int q = 0; q < 3; ++q) {
        int f = gw * 3 + q;                  // 0..3071 = rg(16) x w(4) x m(2) x kt(24)
        int rg = f / 192, r1 = f % 192;
        int w = r1 / 48,  r2 = r1 % 48;
        int m = r2 / 24,  kt = r2 % 24;
        int grow = w * 512 + rg * 32 + m * 16 + (lane & 15);
        int k0 = kt * 32 + ((lane >> 4) << 3);
        BQ pk;
        #pragma unroll
        for (int j = 0; j < 8; ++j) {
            int k = k0 + j;
            float wv = (k < EMBD) ? W_ih[(size_t)grow * EMBD + k]
                                  : W_hh[(size_t)grow * HIDD + (k - EMBD)];
            pk.u[j] = f2bf(wv);
        }
        ((short8x*)pW)[((size_t)f) * 64 + lane] = pk.v;
    }
    // per-batch state init (b = wid): x for step 0 (row 0), h=0, base=0
    int b = wid;
    int tok = xs[b];   // row 0
    float ev = embW[(size_t)tok * EMBD + t] * mask[(size_t)b * EMBD + t];
    xh0[(size_t)b * KDIM + t] = f2bf(ev);
    for (int e = t; e < HIDD; e += 256) xh0[(size_t)b * KDIM + EMBD + e] = 0;
    if (t == 0) base_rows[b] = 0;
    if (t < 32) flags[wid * 32 + t] = 0u;
}

// ---------------------------------------------------------------------------
// Persistent kernel. 256 WGs = 16 col-blocks (cb, 16 cols) x 16 row-groups
// (rg, 128 gate rows = 32 units x 4 gates). WG owns col colg=cb*16+rg for
// gather/boundary/loss. Staging: 16B sc1 loads (4x fewer requests than R7).
// Barrier: 16 padded flags per col-block. R7's exact math -> bit-identical.
// ---------------------------------------------------------------------------
__global__ __launch_bounds__(256, 1) void persistent_kernel(
    const unsigned short* __restrict__ pW,
    unsigned short* __restrict__ xh,           // 2 double-buffered [256][768]
    int* __restrict__ base_rows,
    const float* __restrict__ b_ih, const float* __restrict__ b_hh,
    const int* __restrict__ xs, const float* __restrict__ embW,
    const float* __restrict__ mask,
    const float* __restrict__ W_jump, const float* __restrict__ b_jump,
    const float* __restrict__ W_base, const float* __restrict__ b_base,
    const float* __restrict__ gumbel,
    float* __restrict__ lp_arr, float* __restrict__ base_arr,
    const float* __restrict__ W_out, const float* __restrict__ b_out,
    const int* __restrict__ tcls,
    float* __restrict__ loss_arr, unsigned* __restrict__ flags)
{
    __shared__ u64 Bsh[16 * 193];                 // [16 cols][772 shorts pad]; x=0..63, h=64..191 (u64)
    __shared__ float gates[4][32][17];            // [gate][unit][col+pad]
    __shared__ __align__(8) unsigned short hstage[16][32];   // [col][unit]
    __shared__ __align__(8) unsigned short xstage[256];
    __shared__ float zsh[42];
    __shared__ int rowsh, nbrsh;

    const int wg = blockIdx.x;
    const int cb = wg >> 4, rg = wg & 15;
    const int C0 = cb * 16;                       // first col of block
    const int colg = C0 + rg;                     // owned column
    const int tid = threadIdx.x, lane = tid & 63, w = tid >> 6;

    // --- A fragments resident: 48 x short8x per wave (gate w, 2 m-tiles) ---
    short8x A[48];
    {
        const short8x* Ab = ((const short8x*)pW) + ((size_t)(rg * 4 + w) * 48) * 64 + lane;
        #pragma unroll
        for (int f = 0; f < 48; ++f) A[f] = Ab[f * 64];
    }

    // --- elementwise mapping: unit u = tid>>3 (32), two cols c0=(tid&7)*2 ---
    const int u = tid >> 3;
    const int c0 = (tid & 7) << 1;
    const int hid = rg * 32 + u;
    const float bi  = b_ih[hid]        + b_hh[hid];
    const float bf_ = b_ih[512 + hid]  + b_hh[512 + hid];
    const float bgt = b_ih[1024 + hid] + b_hh[1024 + hid];
    const float bo  = b_ih[1536 + hid] + b_hh[1536 + hid];

    float cf0 = 0.f, cf1 = 0.f, hf0 = 0.f, hf1 = 0.f;
    int brc0 = 0, brc1 = 0, rowg = 0;

    unsigned bar = 0;
    const size_t XH = (size_t)BATCH * KDIM;
    int p = 0;

    for (int n = 0; n < 5; ++n) {
        for (int i = 0; i <= 20; ++i) {
            const unsigned short* xin  = xh + (size_t)p * XH;
            unsigned short*       xout = xh + (size_t)(p ^ 1) * XH;

            // (1) owner's next-x gather loads (read-only, plain, early)
            float ge = 0.f, gm = 0.f;
            if (i < 20) {
                int row = rowg + i + 1; if (row > LSEQ - 1) row = LSEQ - 1;
                int tok = xs[(size_t)row * BATCH + colg];
                ge = embW[(size_t)tok * EMBD + tid];
                gm = mask[((size_t)row * BATCH + colg) * EMBD + tid];
            }

            // (2) stage B block (16 cols x 768 k = 1536 x 16B) sc1 -> LDS
            {
                const unsigned char* gb = (const unsigned char*)(xin + (size_t)C0 * KDIM);
                BX tmp[6];
                #pragma unroll
                for (int j = 0; j < 6; ++j)
                    ALD16(tmp[j].v, gb + ((size_t)(j * 256 + tid) << 4));
                asm volatile("s_waitcnt vmcnt(0)" ::: "memory");
                __builtin_amdgcn_sched_barrier(0);
                #pragma unroll
                for (int j = 0; j < 6; ++j) {
                    unsigned g = (unsigned)(j * 256 + tid);   // 0..1535
                    unsigned col = g / 96u, o16 = g % 96u;
                    u64* d = &Bsh[col * 193u + o16 * 2u];
                    d[0] = tmp[j].q[0];
                    d[1] = tmp[j].q[1];
                }
            }
            __syncthreads();

            // (3) MFMA: wave w = gate w; 2 m-tiles x 1 n-tile; dual kt chains
            f32x4 e0 = {0,0,0,0}, o0 = {0,0,0,0};
            f32x4 e1 = {0,0,0,0}, o1 = {0,0,0,0};
            {
                const u64* bc = &Bsh[(size_t)(lane & 15) * 193 + ((lane >> 4) << 1)];
                #pragma unroll
                for (int kt = 0; kt < 24; kt += 2) {
                    BQ qe, qo;
                    qe.q[0] = bc[kt * 8];     qe.q[1] = bc[kt * 8 + 1];
                    qo.q[0] = bc[kt * 8 + 8]; qo.q[1] = bc[kt * 8 + 9];
                    e0 = __builtin_amdgcn_mfma_f32_16x16x32_bf16(A[kt],          qe.v, e0, 0, 0, 0);
                    e1 = __builtin_amdgcn_mfma_f32_16x16x32_bf16(A[24 + kt],     qe.v, e1, 0, 0, 0);
                    o0 = __builtin_amdgcn_mfma_f32_16x16x32_bf16(A[kt + 1],      qo.v, o0, 0, 0, 0);
                    o1 = __builtin_amdgcn_mfma_f32_16x16x32_bf16(A[24 + kt + 1], qo.v, o1, 0, 0, 0);
                }
            }
            f32x4 acc0 = e0 + o0, acc1 = e1 + o1;   // m-tile 0, m-tile 1
            {
                int ur = (lane >> 4) << 2;
                int cl = lane & 15;
                #pragma unroll
                for (int v = 0; v < 4; ++v) {   // D: row=(lane>>4)*4+v, col=lane&15
                    gates[w][ur + v][cl]      = acc0[v];
                    gates[w][16 + ur + v][cl] = acc1[v];
                }
            }
            __syncthreads();

            // (4) elementwise LSTM on resident state (2 cols)
            {
                bool fp = (brc0 + i) >= LSEQ;
                float gi = gates[0][u][c0] + bi;
                float gf = gates[1][u][c0] + bf_;
                float gc = gates[2][u][c0] + bgt;
                float go = gates[3][u][c0] + bo;
                float c2 = sigm(gf) * cf0 + sigm(gi) * tanhf(gc);
                float h2 = sigm(go) * tanhf(c2);
                if (!fp) { cf0 = c2; hf0 = h2; }
                hstage[c0][u] = f2bf(hf0);
            }
            {
                bool fp = (brc1 + i) >= LSEQ;
                float gi = gates[0][u][c0 + 1] + bi;
                float gf = gates[1][u][c0 + 1] + bf_;
                float gc = gates[2][u][c0 + 1] + bgt;
                float go = gates[3][u][c0 + 1] + bo;
                float c2 = sigm(gf) * cf1 + sigm(gi) * tanhf(gc);
                float h2 = sigm(go) * tanhf(c2);
                if (!fp) { cf1 = c2; hf1 = h2; }
                hstage[c0 + 1][u] = f2bf(hf1);
            }
            if (i < 20) xstage[tid] = f2bf(ge * gm);
            __syncthreads();

            // (5) agent stores: h slice (32 units x 16 cols) + owner's x
            if (tid < 128) {
                int col = tid >> 3, qd = tid & 7;
                u64 hv = ((const u64*)&hstage[col][0])[qd];
                ast((u64*)(xout + (size_t)(C0 + col) * KDIM + EMBD + rg * 32) + qd, hv);
            }
            if (i < 20 && tid < 64) {
                ast((u64*)(xout + (size_t)colg * KDIM) + tid, ((const u64*)xstage)[tid]);
            }
            p ^= 1;

            // (6) per-col-block barrier (16 padded flags)
            ++bar;
            asm volatile("s_waitcnt vmcnt(0) lgkmcnt(0)" ::: "memory");
            __syncthreads();
            if (tid == 0) __hip_atomic_store(&flags[wg * 32], bar, RLX, AGT);
            if (tid < 16) {
                while (__hip_atomic_load(&flags[(cb * 16 + tid) * 32], RLX, AGT) < bar)
                    __builtin_amdgcn_s_sleep(1);
            }
            __syncthreads();

            if (i == 20) {
                // ---------------- boundary (owned col) ----------------------
                unsigned short* xcur = xh + (size_t)p * XH;
                BX hv;
                {
                    const unsigned char* hq =
                        (const unsigned char*)(xcur + (size_t)colg * KDIM + EMBD + lane * 8);
                    ALD16(hv.v, hq);
                    asm volatile("s_waitcnt vmcnt(0)" ::: "memory");
                    __builtin_amdgcn_sched_barrier(0);
                }
                float hf[8];
                #pragma unroll
                for (int q = 0; q < 8; ++q) hf[q] = bf2f(hv.u[q]);

                for (int r = w; r < 42; r += 4) {
                    const float* wr = (r < NJ) ? (W_jump + (size_t)r * HIDD) : W_base;
                    const float4* wp = (const float4*)(wr + lane * 8);
                    float4 w0 = wp[0], w1 = wp[1];
                    float acc = w0.x*hf[0] + w0.y*hf[1] + w0.z*hf[2] + w0.w*hf[3]
                              + w1.x*hf[4] + w1.y*hf[5] + w1.z*hf[6] + w1.w*hf[7];
                    #pragma unroll
                    for (int off = 32; off > 0; off >>= 1) acc += __shfl_down(acc, off, 64);
                    if (lane == 0) zsh[r] = acc + ((r < NJ) ? b_jump[r] : b_base[0]);
                }
                __syncthreads();

                if (tid == 0) {
                    const float* g = gumbel + ((size_t)n * BATCH + colg) * NJ;
                    float m = -1e30f, mg = -1e30f; int jm = 0;
                    for (int r = 0; r < NJ; ++r) {
                        float z = zsh[r];
                        if (z > m) m = z;
                        float zg = z + g[r];
                        if (zg > mg) { mg = zg; jm = r; }   // strict > tiebreak
                    }
                    float s = 0.0f;
                    for (int r = 0; r < NJ; ++r) s += expf(zsh[r] - m);
                    float lse = m + logf(s);
                    int br = rowg;
                    bool fp = (br + 20) >= LSEQ;
                    lp_arr[n * BATCH + colg]   = fp ? 0.0f : (zsh[jm] - lse);  // plain: own-WG consumer
                    base_arr[n * BATCH + colg] = zsh[41];
                    int reff = br + 20; if (reff > LSEQ - 1) reff = LSEQ - 1;
                    int nbr = (jm == 0) ? LSEQ : (reff + jm);
                    __hip_atomic_store(&base_rows[colg], nbr, RLX, AGT);
                    nbrsh = nbr;
                    rowsh = (nbr > LSEQ - 1) ? (LSEQ - 1) : nbr;
                }
                __syncthreads();

                if (n < 4) {                    // gather first x of next outer
                    int row = rowsh;
                    int tok = xs[(size_t)row * BATCH + colg];
                    float ev = embW[(size_t)tok * EMBD + tid] *
                               mask[((size_t)row * BATCH + colg) * EMBD + tid];
                    xstage[tid] = f2bf(ev);
                }
                rowg = nbrsh;
                __syncthreads();
                if (n < 4 && tid < 64) {
                    ast((u64*)(xcur + (size_t)colg * KDIM) + tid, ((const u64*)xstage)[tid]);
                }

                // barrier #2: publish base_rows, then refresh brc0/brc1
                ++bar;
                asm volatile("s_waitcnt vmcnt(0) lgkmcnt(0)" ::: "memory");
                __syncthreads();
                if (tid == 0) __hip_atomic_store(&flags[wg * 32], bar, RLX, AGT);
                if (tid < 16) {
                    while (__hip_atomic_load(&flags[(cb * 16 + tid) * 32], RLX, AGT) < bar)
                        __builtin_amdgcn_s_sleep(1);
                }
                __syncthreads();
                brc0 = __hip_atomic_load(&base_rows[C0 + c0],     RLX, AGT);
                brc1 = __hip_atomic_load(&base_rows[C0 + c0 + 1], RLX, AGT);
            }
        }
    }

    // ---------------- final: per-col loss (owned col) -----------------------
    {
        const unsigned short* xcur = xh + (size_t)p * XH;
        BX hv;
        {
            const unsigned char* hq =
                (const unsigned char*)(xcur + (size_t)colg * KDIM + EMBD + lane * 8);
            ALD16(hv.v, hq);
            asm volatile("s_waitcnt vmcnt(0)" ::: "memory");
            __builtin_amdgcn_sched_barrier(0);
        }
        float hf[8];
        #pragma unroll
        for (int q = 0; q < 8; ++q) hf[q] = bf2f(hv.u[q]);

        for (int r = w; r < 5; r += 4) {
            const float4* wp = (const float4*)(W_out + (size_t)r * HIDD + lane * 8);
            float4 w0 = wp[0], w1 = wp[1];
            float acc = w0.x*hf[0] + w0.y*hf[1] + w0.z*hf[2] + w0.w*hf[3]
                      + w1.x*hf[4] + w1.y*hf[5] + w1.z*hf[6] + w1.w*hf[7];
            #pragma unroll
            for (int off = 32; off > 0; off >>= 1) acc += __shfl_down(acc, off, 64);
            if (lane == 0) zsh[r] = acc + b_out[r];
        }
        __syncthreads();

        if (tid == 0) {
            float y[5];
            #pragma unroll
            for (int c = 0; c < 5; ++c) y[c] = zsh[c];
            float m = y[0]; int am = 0;
            for (int c = 1; c < 5; ++c) if (y[c] > m) { m = y[c]; am = c; }
            float s = 0.0f;
            for (int c = 0; c < 5; ++c) s += expf(y[c] - m);
            float lse = m + logf(s);
            int tb = tcls[colg];
            float nll_p  = -(y[tb] - lse) * (1.0f / BATCH);
            float reward = (am == tb) ? 1.0f : -1.0f;
            float rp = 0.0f, mp = 0.0f;
            for (int nn = 0; nn < 5; ++nn) {
                float bs = base_arr[nn * BATCH + colg];
                float lp = lp_arr[nn * BATCH + colg];
                rp += -(reward - bs) * lp;
                float d = bs - reward;
                mp += d * d;
            }
            loss_arr[colg] = nll_p + rp * (1.0f / (5.0f * BATCH)) + mp;
        }
    }
}

// ---------------------------------------------------------------------------
__global__ __launch_bounds__(256) void reduce_kernel(
    const float* __restrict__ loss_arr, float* __restrict__ out)
{
    __shared__ float red[256];
    int t = threadIdx.x;
    red[t] = loss_arr[t];
    __syncthreads();
    for (int off = 128; off > 0; off >>= 1) {
        if (t < off) red[t] += red[t + off];
        __syncthreads();
    }
    if (t == 0) out[0] = red[0];
}

// ---------------------------------------------------------------------------
extern "C" void kernel_launch(void* const* d_in, const int* in_sizes, int n_in,
                              void* d_out, int out_size, void* d_ws, size_t ws_size,
                              hipStream_t stream)
{
    (void)in_sizes; (void)n_in; (void)out_size; (void)ws_size;
    const int*   xs     = (const int*)d_in[0];
    const int*   tcls   = (const int*)d_in[2];
    const float* embW   = (const float*)d_in[3];
    const float* W_ih   = (const float*)d_in[4];
    const float* W_hh   = (const float*)d_in[5];
    const float* b_ih   = (const float*)d_in[6];
    const float* b_hh   = (const float*)d_in[7];
    const float* W_out  = (const float*)d_in[8];
    const float* b_out  = (const float*)d_in[9];
    const float* W_jump = (const float*)d_in[10];
    const float* b_jump = (const float*)d_in[11];
    const float* W_base = (const float*)d_in[12];
    const float* b_base = (const float*)d_in[13];
    const float* mask   = (const float*)d_in[14];
    const float* gumbel = (const float*)d_in[15];

    char* wsp = (char*)d_ws;
    unsigned short* pW  = (unsigned short*)(wsp);                 // 3,145,728 B
    unsigned short* xh  = (unsigned short*)(wsp + 3145728);       //   786,432 B
    int*      base_rows = (int*)(wsp + 3932160);                  //     1,024 B
    float*    lp_arr    = (float*)(wsp + 3933184);                //     5,120 B
    float*    base_arr  = (float*)(wsp + 3938304);                //     5,120 B
    float*    loss_arr  = (float*)(wsp + 3943424);                //     1,024 B
    unsigned* flags     = (unsigned*)(wsp + 3944448);             //    32,768 B
    float*    outp      = (float*)d_out;

    prologue_kernel<<<256, 256, 0, stream>>>(W_ih, W_hh, xs, embW, mask,
                                             pW, xh, base_rows, flags);

    void* args[] = {
        (void*)&pW, (void*)&xh, (void*)&base_rows,
        (void*)&b_ih, (void*)&b_hh, (void*)&xs, (void*)&embW, (void*)&mask,
        (void*)&W_jump, (void*)&b_jump, (void*)&W_base, (void*)&b_base,
        (void*)&gumbel, (void*)&lp_arr, (void*)&base_arr,
        (void*)&W_out, (void*)&b_out, (void*)&tcls,
        (void*)&loss_arr, (void*)&flags
    };
    hipError_t err = hipLaunchCooperativeKernel((const void*)persistent_kernel,
                                                dim3(256), dim3(256), args, 0, stream);
    if (err != hipSuccess) {
        // Plain launch fallback: 256 WGs at 1/CU are co-resident; barrier is
        // monotonic, so semantics are unchanged.
        persistent_kernel<<<256, 256, 0, stream>>>(
            pW, xh, base_rows, b_ih, b_hh, xs, embW, mask,
            W_jump, b_jump, W_base, b_base, gumbel, lp_arr, base_arr,
            W_out, b_out, tcls, loss_arr, flags);
    }
    reduce_kernel<<<1, 256, 0, stream>>>(loss_arr, outp);
}

// Round 11
// 483.571 us; speedup vs baseline: 2.2172x; 1.0285x over previous
//
#include <hip/hip_runtime.h>

#define LSEQ 400
#define BATCH 256
#define EMBD 256
#define HIDD 512
#define NJ 41      // K+1
#define RLX __ATOMIC_RELAXED
#define AGT __HIP_MEMORY_SCOPE_AGENT

typedef __attribute__((ext_vector_type(8))) short short8x;
typedef __attribute__((ext_vector_type(4))) float f32x4;
typedef __attribute__((ext_vector_type(4))) unsigned int u32x4;
typedef unsigned long long u64;

union BQ { short8x v; unsigned short u[8]; u64 q[2]; };
union BX { u32x4 v; unsigned short u[8]; u64 q[2]; };

__device__ __forceinline__ float bf2f(unsigned short u) {
    union { unsigned int i; float f; } v; v.i = ((unsigned int)u) << 16; return v.f;
}
__device__ __forceinline__ unsigned short f2bf(float f) {
    union { float f; unsigned int i; } v; v.f = f;
    unsigned int x = v.i;
    return (unsigned short)((x + 0x7fffu + ((x >> 16) & 1u)) >> 16);
}
__device__ __forceinline__ float sigm(float x) { return 1.0f / (1.0f + __expf(-x)); }
__device__ __forceinline__ u64 pack4(float4 e, float4 m) {
    return (u64)f2bf(e.x * m.x) | ((u64)f2bf(e.y * m.y) << 16)
         | ((u64)f2bf(e.z * m.z) << 32) | ((u64)f2bf(e.w * m.w) << 48);
}

// agent-coherent 16B ops (sc1 = coherent point, same class as compiler's
// relaxed agent atomics — proven R10)
#define ALD16(dst, addr) \
    asm volatile("global_load_dwordx4 %0, %1, off sc1" : "=&v"(dst) : "v"(addr) : "memory")
#define AST16(addr, src) \
    asm volatile("global_store_dwordx4 %0, %1, off sc1" :: "v"(addr), "v"(src) : "memory")

// ---------------------------------------------------------------------------
// Prologue: pack W into bf16 fragments [rg(16)][w(4)][m(2)][kt(24)][lane(64)]
// (proven bijection); zero h buffer 0, base_rows, flags.
// ---------------------------------------------------------------------------
__global__ __launch_bounds__(256) void prologue_kernel(
    const float* __restrict__ W_ih, const float* __restrict__ W_hh,
    unsigned short* __restrict__ pW, unsigned short* __restrict__ hbuf,
    int* __restrict__ base_rows, unsigned* __restrict__ flags)
{
    int wid = blockIdx.x, t = threadIdx.x;
    int lane = t & 63, subw = t >> 6;
    int gw = wid * 4 + subw;                 // 0..1023
    for (int q = 0; q < 3; ++q) {
        int f = gw * 3 + q;                  // 0..3071 = rg(16) x w(4) x m(2) x kt(24)
        int rg = f / 192, r1 = f % 192;
        int w = r1 / 48,  r2 = r1 % 48;
        int m = r2 / 24,  kt = r2 % 24;
        int grow = w * 512 + rg * 32 + m * 16 + (lane & 15);
        int k0 = kt * 32 + ((lane >> 4) << 3);
        BQ pk;
        #pragma unroll
        for (int j = 0; j < 8; ++j) {
            int k = k0 + j;
            float wv = (k < EMBD) ? W_ih[(size_t)grow * EMBD + k]
                                  : W_hh[(size_t)grow * HIDD + (k - EMBD)];
            pk.u[j] = f2bf(wv);
        }
        ((short8x*)pW)[((size_t)f) * 64 + lane] = pk.v;
    }
    // zero h(0) in buffer 0 (col = wid)
    if (t < 128) ((u64*)hbuf)[(size_t)wid * 128 + t] = 0ull;
    if (t == 0) base_rows[wid] = 0;
    if (t < 32) flags[wid * 32 + t] = 0u;
}

// ---------------------------------------------------------------------------
// Persistent kernel. 256 WGs = 16 col-blocks (cb, 16 cols) x 16 row-groups
// (rg, 128 gate rows). Only h (512k) crosses WGs (16B sc1); x is gathered
// locally per WG for all 16 cols (rows deterministic from brs). x-part MFMA
// runs BEFORE the flag poll to hide the producers' post RT.
// ---------------------------------------------------------------------------
__global__ __launch_bounds__(256, 1) void persistent_kernel(
    const unsigned short* __restrict__ pW,
    unsigned short* __restrict__ hbuf,         // 2 x [256 cols][512] bf16
    int* __restrict__ base_rows,
    const float* __restrict__ b_ih, const float* __restrict__ b_hh,
    const int* __restrict__ xs, const float* __restrict__ embW,
    const float* __restrict__ mask,
    const float* __restrict__ W_jump, const float* __restrict__ b_jump,
    const float* __restrict__ W_base, const float* __restrict__ b_base,
    const float* __restrict__ gumbel,
    float* __restrict__ lp_arr, float* __restrict__ base_arr,
    const float* __restrict__ W_out, const float* __restrict__ b_out,
    const int* __restrict__ tcls,
    float* __restrict__ loss_arr, unsigned* __restrict__ flags)
{
    __shared__ u64 Bsh[16 * 193];                 // [16 cols]; x = u64 0..63, h = 64..191
    __shared__ float gates[4][32][17];            // [gate][unit][col+pad]
    __shared__ __align__(8) unsigned short hstage[16][32];   // [col][unit]
    __shared__ int brs[16];                       // base rows of this block's cols
    __shared__ float zsh[42];

    const int wg = blockIdx.x;
    const int cb = wg >> 4, rg = wg & 15;
    const int C0 = cb * 16;
    const int colg = C0 + rg;                     // owned column
    const int tid = threadIdx.x, lane = tid & 63, w = tid >> 6;

    // --- A fragments resident: 48 x short8x per wave (gate w, 2 m-tiles) ---
    short8x A[48];
    {
        const short8x* Ab = ((const short8x*)pW) + ((size_t)(rg * 4 + w) * 48) * 64 + lane;
        #pragma unroll
        for (int f = 0; f < 48; ++f) A[f] = Ab[f * 64];
    }

    // --- elementwise mapping: unit u = tid>>3 (32), two cols c0=(tid&7)*2 ---
    const int u = tid >> 3;
    const int c0 = (tid & 7) << 1;
    const int hid = rg * 32 + u;
    const float bi  = b_ih[hid]        + b_hh[hid];
    const float bf_ = b_ih[512 + hid]  + b_hh[512 + hid];
    const float bgt = b_ih[1024 + hid] + b_hh[1024 + hid];
    const float bo  = b_ih[1536 + hid] + b_hh[1536 + hid];

    // --- gather mapping: col gcol = tid>>4, segment gseg = tid&15 (16 elems)---
    const int gcol = tid >> 4, gseg = tid & 15;
    u64* const gdst = &Bsh[(size_t)gcol * 193 + gseg * 4];

    const u64* const bc = &Bsh[(size_t)(lane & 15) * 193 + ((lane >> 4) << 1)];

    float cf0 = 0.f, cf1 = 0.f, hf0 = 0.f, hf1 = 0.f;
    int brc0 = 0, brc1 = 0;

    unsigned bar = 0;
    const size_t HB = (size_t)BATCH * HIDD;       // shorts per h buffer
    int p = 0;

    // --- init: brs=0; gather x(0) (row 0) for all 16 cols locally ---
    if (tid < 16) brs[tid] = 0;
    __syncthreads();
    {
        int tok = xs[C0 + gcol];                  // row 0
        const float4* ep = (const float4*)(embW + (size_t)tok * EMBD + gseg * 16);
        const float4* mp = (const float4*)(mask + ((size_t)(C0 + gcol)) * EMBD + gseg * 16);
        #pragma unroll
        for (int s = 0; s < 4; ++s) gdst[s] = pack4(ep[s], mp[s]);
    }
    __syncthreads();

    for (int n = 0; n < 5; ++n) {
        for (int i = 0; i <= 20; ++i) {
            const unsigned short* hin  = hbuf + (size_t)p * HB;
            unsigned short*       hout = hbuf + (size_t)(p ^ 1) * HB;

            // (0) x-part MFMA (kt 0..7) on locally-gathered x — pre-poll work
            f32x4 e0 = {0,0,0,0}, o0 = {0,0,0,0};
            f32x4 e1 = {0,0,0,0}, o1 = {0,0,0,0};
            #pragma unroll
            for (int kt = 0; kt < 8; kt += 2) {
                BQ qe, qo;
                qe.q[0] = bc[kt * 8];     qe.q[1] = bc[kt * 8 + 1];
                qo.q[0] = bc[kt * 8 + 8]; qo.q[1] = bc[kt * 8 + 9];
                e0 = __builtin_amdgcn_mfma_f32_16x16x32_bf16(A[kt],          qe.v, e0, 0, 0, 0);
                e1 = __builtin_amdgcn_mfma_f32_16x16x32_bf16(A[24 + kt],     qe.v, e1, 0, 0, 0);
                o0 = __builtin_amdgcn_mfma_f32_16x16x32_bf16(A[kt + 1],      qo.v, o0, 0, 0, 0);
                o1 = __builtin_amdgcn_mfma_f32_16x16x32_bf16(A[24 + kt + 1], qo.v, o1, 0, 0, 0);
            }

            // (2) poll h(i) published (posted at end of previous step)
            if (tid < 16) {
                while (__hip_atomic_load(&flags[(cb * 16 + tid) * 32], RLX, AGT) < bar)
                    __builtin_amdgcn_s_sleep(1);
            }
            __syncthreads();

            // (3) stage h (16 cols x 512 = 1024 x 16B) sc1 -> LDS
            {
                const unsigned char* hb = (const unsigned char*)(hin + (size_t)C0 * HIDD);
                BX tmp[4];
                #pragma unroll
                for (int j = 0; j < 4; ++j)
                    ALD16(tmp[j].v, hb + ((size_t)(j * 256 + tid) << 4));
                asm volatile("s_waitcnt vmcnt(0)" ::: "memory");
                __builtin_amdgcn_sched_barrier(0);
                #pragma unroll
                for (int j = 0; j < 4; ++j) {
                    unsigned g = (unsigned)(j * 256 + tid);   // 0..1023
                    u64* d = &Bsh[(g >> 6) * 193u + 64u + (g & 63u) * 2u];
                    d[0] = tmp[j].q[0];
                    d[1] = tmp[j].q[1];
                }
            }
            __syncthreads();

            // (4b) issue next-x gather loads (consumed at (8))
            float4 ge[4], gm[4];
            if (i < 20) {
                int row = brs[gcol] + i + 1; if (row > LSEQ - 1) row = LSEQ - 1;
                int tok = xs[(size_t)row * BATCH + C0 + gcol];
                const float4* ep = (const float4*)(embW + (size_t)tok * EMBD + gseg * 16);
                const float4* mp = (const float4*)(mask + ((size_t)row * BATCH + C0 + gcol) * EMBD + gseg * 16);
                #pragma unroll
                for (int s = 0; s < 4; ++s) { ge[s] = ep[s]; gm[s] = mp[s]; }
            }

            // (5) h-part MFMA (kt 8..23)
            #pragma unroll
            for (int kt = 8; kt < 24; kt += 2) {
                BQ qe, qo;
                qe.q[0] = bc[kt * 8];     qe.q[1] = bc[kt * 8 + 1];
                qo.q[0] = bc[kt * 8 + 8]; qo.q[1] = bc[kt * 8 + 9];
                e0 = __builtin_amdgcn_mfma_f32_16x16x32_bf16(A[kt],          qe.v, e0, 0, 0, 0);
                e1 = __builtin_amdgcn_mfma_f32_16x16x32_bf16(A[24 + kt],     qe.v, e1, 0, 0, 0);
                o0 = __builtin_amdgcn_mfma_f32_16x16x32_bf16(A[kt + 1],      qo.v, o0, 0, 0, 0);
                o1 = __builtin_amdgcn_mfma_f32_16x16x32_bf16(A[24 + kt + 1], qo.v, o1, 0, 0, 0);
            }
            f32x4 acc0 = e0 + o0, acc1 = e1 + o1;
            {
                int ur = (lane >> 4) << 2;
                int cl = lane & 15;
                #pragma unroll
                for (int v = 0; v < 4; ++v) {   // D: row=(lane>>4)*4+v, col=lane&15
                    gates[w][ur + v][cl]      = acc0[v];
                    gates[w][16 + ur + v][cl] = acc1[v];
                }
            }
            __syncthreads();

            // (8) elementwise LSTM (2 cols) + pack next-x into Bsh x-region
            {
                bool fp = (brc0 + i) >= LSEQ;
                float gi = gates[0][u][c0] + bi;
                float gf = gates[1][u][c0] + bf_;
                float gc = gates[2][u][c0] + bgt;
                float go = gates[3][u][c0] + bo;
                float c2 = sigm(gf) * cf0 + sigm(gi) * tanhf(gc);
                float h2 = sigm(go) * tanhf(c2);
                if (!fp) { cf0 = c2; hf0 = h2; }
                hstage[c0][u] = f2bf(hf0);
            }
            {
                bool fp = (brc1 + i) >= LSEQ;
                float gi = gates[0][u][c0 + 1] + bi;
                float gf = gates[1][u][c0 + 1] + bf_;
                float gc = gates[2][u][c0 + 1] + bgt;
                float go = gates[3][u][c0 + 1] + bo;
                float c2 = sigm(gf) * cf1 + sigm(gi) * tanhf(gc);
                float h2 = sigm(go) * tanhf(c2);
                if (!fp) { cf1 = c2; hf1 = h2; }
                hstage[c0 + 1][u] = f2bf(hf1);
            }
            if (i < 20) {
                #pragma unroll
                for (int s = 0; s < 4; ++s) gdst[s] = pack4(ge[s], gm[s]);
            }
            __syncthreads();

            // (10) h stores (16B sc1), drain, post flag
            if (tid < 64) {
                int col = tid >> 2, part = tid & 3;
                const u64* hs = (const u64*)&hstage[col][0];
                BX v; v.q[0] = hs[part * 2]; v.q[1] = hs[part * 2 + 1];
                unsigned short* dst = hout + (size_t)(C0 + col) * HIDD + rg * 32 + part * 16;
                AST16(dst, v.v);
            }
            p ^= 1;
            ++bar;
            asm volatile("s_waitcnt vmcnt(0) lgkmcnt(0)" ::: "memory");
            __syncthreads();
            if (tid == 0) __hip_atomic_store(&flags[wg * 32], bar, RLX, AGT);

            if (i == 20) {
                // -------- boundary (owned col), single exchange round --------
                if (tid < 16) {
                    while (__hip_atomic_load(&flags[(cb * 16 + tid) * 32], RLX, AGT) < bar)
                        __builtin_amdgcn_s_sleep(1);
                }
                __syncthreads();
                const unsigned short* hcur = hbuf + (size_t)p * HB;
                BX hv;
                ALD16(hv.v, (const unsigned char*)(hcur + (size_t)colg * HIDD + lane * 8));
                asm volatile("s_waitcnt vmcnt(0)" ::: "memory");
                __builtin_amdgcn_sched_barrier(0);
                float hf[8];
                #pragma unroll
                for (int q = 0; q < 8; ++q) hf[q] = bf2f(hv.u[q]);

                for (int r = w; r < 42; r += 4) {
                    const float* wr = (r < NJ) ? (W_jump + (size_t)r * HIDD) : W_base;
                    const float4* wp = (const float4*)(wr + lane * 8);
                    float4 w0 = wp[0], w1 = wp[1];
                    float acc = w0.x*hf[0] + w0.y*hf[1] + w0.z*hf[2] + w0.w*hf[3]
                              + w1.x*hf[4] + w1.y*hf[5] + w1.z*hf[6] + w1.w*hf[7];
                    #pragma unroll
                    for (int off = 32; off > 0; off >>= 1) acc += __shfl_down(acc, off, 64);
                    if (lane == 0) zsh[r] = acc + ((r < NJ) ? b_jump[r] : b_base[0]);
                }
                __syncthreads();

                if (tid == 0) {
                    const float* g = gumbel + ((size_t)n * BATCH + colg) * NJ;
                    float m = -1e30f, mg = -1e30f; int jm = 0;
                    for (int r = 0; r < NJ; ++r) {
                        float z = zsh[r];
                        if (z > m) m = z;
                        float zg = z + g[r];
                        if (zg > mg) { mg = zg; jm = r; }   // strict > tiebreak
                    }
                    float s = 0.0f;
                    for (int r = 0; r < NJ; ++r) s += expf(zsh[r] - m);
                    float lse = m + logf(s);
                    int br = brs[rg];                       // own OLD base row
                    bool fp = (br + 20) >= LSEQ;
                    lp_arr[n * BATCH + colg]   = fp ? 0.0f : (zsh[jm] - lse);
                    base_arr[n * BATCH + colg] = zsh[41];
                    int reff = br + 20; if (reff > LSEQ - 1) reff = LSEQ - 1;
                    int nbr = (jm == 0) ? LSEQ : (reff + jm);
                    __hip_atomic_store(&base_rows[colg], nbr, RLX, AGT);
                }
                __syncthreads();

                // one exchange round: publish base_rows to the group
                ++bar;
                asm volatile("s_waitcnt vmcnt(0) lgkmcnt(0)" ::: "memory");
                __syncthreads();
                if (tid == 0) __hip_atomic_store(&flags[wg * 32], bar, RLX, AGT);
                if (tid < 16) {
                    while (__hip_atomic_load(&flags[(cb * 16 + tid) * 32], RLX, AGT) < bar)
                        __builtin_amdgcn_s_sleep(1);
                }
                __syncthreads();
                if (tid < 16)
                    brs[tid] = __hip_atomic_load(&base_rows[C0 + tid], RLX, AGT);
                __syncthreads();
                brc0 = brs[c0];
                brc1 = brs[c0 + 1];
                if (n < 4) {                    // gather x(0) of next outer (local)
                    int row = brs[gcol]; if (row > LSEQ - 1) row = LSEQ - 1;
                    int tok = xs[(size_t)row * BATCH + C0 + gcol];
                    const float4* ep = (const float4*)(embW + (size_t)tok * EMBD + gseg * 16);
                    const float4* mp = (const float4*)(mask + ((size_t)row * BATCH + C0 + gcol) * EMBD + gseg * 16);
                    #pragma unroll
                    for (int s = 0; s < 4; ++s) gdst[s] = pack4(ep[s], mp[s]);
                }
                __syncthreads();
            }
        }
    }

    // ---------------- final: per-col loss (owned col) -----------------------
    {
        const unsigned short* hcur = hbuf + (size_t)p * HB;
        BX hv;
        ALD16(hv.v, (const unsigned char*)(hcur + (size_t)colg * HIDD + lane * 8));
        asm volatile("s_waitcnt vmcnt(0)" ::: "memory");
        __builtin_amdgcn_sched_barrier(0);
        float hf[8];
        #pragma unroll
        for (int q = 0; q < 8; ++q) hf[q] = bf2f(hv.u[q]);

        for (int r = w; r < 5; r += 4) {
            const float4* wp = (const float4*)(W_out + (size_t)r * HIDD + lane * 8);
            float4 w0 = wp[0], w1 = wp[1];
            float acc = w0.x*hf[0] + w0.y*hf[1] + w0.z*hf[2] + w0.w*hf[3]
                      + w1.x*hf[4] + w1.y*hf[5] + w1.z*hf[6] + w1.w*hf[7];
            #pragma unroll
            for (int off = 32; off > 0; off >>= 1) acc += __shfl_down(acc, off, 64);
            if (lane == 0) zsh[r] = acc + b_out[r];
        }
        __syncthreads();

        if (tid == 0) {
            float y[5];
            #pragma unroll
            for (int c = 0; c < 5; ++c) y[c] = zsh[c];
            float m = y[0]; int am = 0;
            for (int c = 1; c < 5; ++c) if (y[c] > m) { m = y[c]; am = c; }
            float s = 0.0f;
            for (int c = 0; c < 5; ++c) s += expf(y[c] - m);
            float lse = m + logf(s);
            int tb = tcls[colg];
            float nll_p  = -(y[tb] - lse) * (1.0f / BATCH);
            float reward = (am == tb) ? 1.0f : -1.0f;
            float rp = 0.0f, mp = 0.0f;
            for (int nn = 0; nn < 5; ++nn) {
                float bs = base_arr[nn * BATCH + colg];
                float lp = lp_arr[nn * BATCH + colg];
                rp += -(reward - bs) * lp;
                float d = bs - reward;
                mp += d * d;
            }
            loss_arr[colg] = nll_p + rp * (1.0f / (5.0f * BATCH)) + mp;
        }
    }
}

// ---------------------------------------------------------------------------
__global__ __launch_bounds__(256) void reduce_kernel(
    const float* __restrict__ loss_arr, float* __restrict__ out)
{
    __shared__ float red[256];
    int t = threadIdx.x;
    red[t] = loss_arr[t];
    __syncthreads();
    for (int off = 128; off > 0; off >>= 1) {
        if (t < off) red[t] += red[t + off];
        __syncthreads();
    }
    if (t == 0) out[0] = red[0];
}

// ---------------------------------------------------------------------------
extern "C" void kernel_launch(void* const* d_in, const int* in_sizes, int n_in,
                              void* d_out, int out_size, void* d_ws, size_t ws_size,
                              hipStream_t stream)
{
    (void)in_sizes; (void)n_in; (void)out_size; (void)ws_size;
    const int*   xs     = (const int*)d_in[0];
    const int*   tcls   = (const int*)d_in[2];
    const float* embW   = (const float*)d_in[3];
    const float* W_ih   = (const float*)d_in[4];
    const float* W_hh   = (const float*)d_in[5];
    const float* b_ih   = (const float*)d_in[6];
    const float* b_hh   = (const float*)d_in[7];
    const float* W_out  = (const float*)d_in[8];
    const float* b_out  = (const float*)d_in[9];
    const float* W_jump = (const float*)d_in[10];
    const float* b_jump = (const float*)d_in[11];
    const float* W_base = (const float*)d_in[12];
    const float* b_base = (const float*)d_in[13];
    const float* mask   = (const float*)d_in[14];
    const float* gumbel = (const float*)d_in[15];

    char* wsp = (char*)d_ws;
    unsigned short* pW  = (unsigned short*)(wsp);                 // 3,145,728 B
    unsigned short* hbuf= (unsigned short*)(wsp + 3145728);       //   524,288 B
    int*      base_rows = (int*)(wsp + 3670016);                  //     1,024 B
    float*    lp_arr    = (float*)(wsp + 3671040);                //     5,120 B
    float*    base_arr  = (float*)(wsp + 3676160);                //     5,120 B
    float*    loss_arr  = (float*)(wsp + 3681280);                //     1,024 B
    unsigned* flags     = (unsigned*)(wsp + 3682304);             //    32,768 B
    float*    outp      = (float*)d_out;

    prologue_kernel<<<256, 256, 0, stream>>>(W_ih, W_hh, pW, hbuf, base_rows, flags);

    void* args[] = {
        (void*)&pW, (void*)&hbuf, (void*)&base_rows,
        (void*)&b_ih, (void*)&b_hh, (void*)&xs, (void*)&embW, (void*)&mask,
        (void*)&W_jump, (void*)&b_jump, (void*)&W_base, (void*)&b_base,
        (void*)&gumbel, (void*)&lp_arr, (void*)&base_arr,
        (void*)&W_out, (void*)&b_out, (void*)&tcls,
        (void*)&loss_arr, (void*)&flags
    };
    hipError_t err = hipLaunchCooperativeKernel((const void*)persistent_kernel,
                                                dim3(256), dim3(256), args, 0, stream);
    if (err != hipSuccess) {
        // Plain-launch fallback: 256 WGs at 1/CU are co-resident; the barrier
        // is monotonic, so semantics are unchanged.
        persistent_kernel<<<256, 256, 0, stream>>>(
            pW, hbuf, base_rows, b_ih, b_hh, xs, embW, mask,
            W_jump, b_jump, W_base, b_base, gumbel, lp_arr, base_arr,
            W_out, b_out, tcls, loss_arr, flags);
    }
    reduce_kernel<<<1, 256, 0, stream>>>(loss_arr, outp);
}